// Round 4
// baseline (254.362 us; speedup 1.0000x reference)
//
#include <hip/hip_runtime.h>
#include <hip/hip_fp16.h>
#include <cstdint>

#define D 128
#define BLK 256

constexpr float MINN    = 1e-15f;
constexpr float ATCLIP  = 1.0f - 1e-7f;
constexpr float BALLEPS = 4e-3f;

typedef _Float16 f16x8 __attribute__((ext_vector_type(8)));
typedef float    f32x4 __attribute__((ext_vector_type(4)));

union H4 { _Float16 h[4]; uint2 u2; };
union H2U { __half2 h; unsigned u; };

__device__ __forceinline__ float red32(float v) {
    v += __shfl_xor(v, 1);
    v += __shfl_xor(v, 2);
    v += __shfl_xor(v, 4);
    v += __shfl_xor(v, 8);
    v += __shfl_xor(v, 16);
    return v;
}

__device__ __forceinline__ float red64(float v) {
    v += __shfl_xor(v, 1, 64);
    v += __shfl_xor(v, 2, 64);
    v += __shfl_xor(v, 4, 64);
    v += __shfl_xor(v, 8, 64);
    v += __shfl_xor(v, 16, 64);
    v += __shfl_xor(v, 32, 64);
    return v;
}

__device__ __forceinline__ float artanh_(float x) {
    x = fminf(fmaxf(x, -ATCLIP), ATCLIP);
    return atanhf(x);
}

__device__ __forceinline__ float2 h2f(unsigned bits) {
    H2U u; u.u = bits;
    return __half22float2(u.h);
}

// ---------------------------------------------------------------------------
// Kernel 1 (MFMA): h_t = logmap0( mobius_add( mobius_matvec(W,x), expmap0(b) ) )
// 64 nodes/block, 4 waves; wave w owns nodes w*16..w*16+15 (16-col MFMA tile).
// ht written fp16: ht[node*32 + col] packs dims 4col..4col+3.
// ---------------------------------------------------------------------------
__global__ __launch_bounds__(BLK) void k_node_mfma(
    const float* __restrict__ x, const float* __restrict__ W,
    const float* __restrict__ b, uint2* __restrict__ ht, int N)
{
    __shared__ _Float16 Ws[D * 136];    // 34816 B, row-major padded
    __shared__ _Float16 xs[64 * 136];   // 17408 B (later overlaid by out-staging)
    __shared__ float    ps[D];          // p = expmap0(b)
    __shared__ float    xn2s[64];       // exact fp32 ||x||^2 per node

    const int t     = threadIdx.x;
    const int node0 = blockIdx.x * 64;

    // ---- stage W fp32 -> fp16 LDS (coalesced float4 reads, 8B LDS writes)
    for (int it = 0; it < 16; ++it) {
        int lin = it * BLK + t;         // 4096 float4
        int row = lin >> 5;
        int c4  = (lin & 31) * 4;
        float4 v = ((const float4*)W)[lin];
        H4 u;
        u.h[0] = (_Float16)v.x; u.h[1] = (_Float16)v.y;
        u.h[2] = (_Float16)v.z; u.h[3] = (_Float16)v.w;
        *(uint2*)&Ws[row * 136 + c4] = u.u2;
    }

    // ---- stage x fp32 -> fp16 LDS + exact fp32 norms
    for (int it = 0; it < 8; ++it) {
        int lin  = it * BLK + t;        // 2048 float4
        int node = lin >> 5;
        int c4   = (lin & 31) * 4;
        int gn   = node0 + node;
        float4 v = make_float4(0.f, 0.f, 0.f, 0.f);
        if (gn < N) v = ((const float4*)x)[(size_t)gn * 32 + (lin & 31)];
        H4 u;
        u.h[0] = (_Float16)v.x; u.h[1] = (_Float16)v.y;
        u.h[2] = (_Float16)v.z; u.h[3] = (_Float16)v.w;
        *(uint2*)&xs[node * 136 + c4] = u.u2;
        float s = fmaf(v.x, v.x, fmaf(v.y, v.y, fmaf(v.z, v.z, v.w * v.w)));
        s = red32(s);                   // sums the 32-lane subgroup = one node
        if ((t & 31) == 0) xn2s[node] = s;
    }

    // ---- p = expmap0(b): uniform scalar loop
    float bn2 = 0.f;
    for (int k = 0; k < D; ++k) { float v = b[k]; bn2 = fmaf(v, v, bn2); }
    float bnc    = fmaxf(sqrtf(bn2), MINN);
    float bscale = tanhf(bnc) / bnc;
    if (t < D) ps[t] = b[t] * bscale;
    const float y2 = bscale * bscale * bn2;   // ||p||^2
    __syncthreads();

    // ---- MFMA: mx[128 out][16 nodes] per wave
    const int lane = t & 63;
    const int w    = t >> 6;
    const int c    = lane & 15;     // node within wave-tile / W row within m-tile
    const int g    = lane >> 4;     // quad

    f32x4 Cf[8];
#pragma unroll
    for (int mt = 0; mt < 8; ++mt) Cf[mt] = (f32x4){0.f, 0.f, 0.f, 0.f};

    const _Float16* xbase = &xs[(w * 16 + c) * 136];
#pragma unroll
    for (int s = 0; s < 4; ++s) {
        f16x8 Bf = *(const f16x8*)&xbase[s * 32 + g * 8];
#pragma unroll
        for (int mt = 0; mt < 8; ++mt) {
            f16x8 Af = *(const f16x8*)&Ws[(mt * 16 + c) * 136 + s * 32 + g * 8];
            Cf[mt] = __builtin_amdgcn_mfma_f32_16x16x32_f16(Af, Bf, Cf[mt], 0, 0, 0);
        }
    }
    // lane holds mx[mt*16 + g*4 + r][node0 + w*16 + c] in Cf[mt][r]

    // ---- per-node epilogue (node = w*16 + c; 4 lanes per node via quads)
    float pm = 0.f, pd = 0.f;
    const float4* ps4 = (const float4*)ps;
#pragma unroll
    for (int mt = 0; mt < 8; ++mt) {
        float4 pv = ps4[mt * 4 + g];
        pm = fmaf(Cf[mt][0], Cf[mt][0], pm);
        pm = fmaf(Cf[mt][1], Cf[mt][1], pm);
        pm = fmaf(Cf[mt][2], Cf[mt][2], pm);
        pm = fmaf(Cf[mt][3], Cf[mt][3], pm);
        pd = fmaf(Cf[mt][0], pv.x, pd);
        pd = fmaf(Cf[mt][1], pv.y, pd);
        pd = fmaf(Cf[mt][2], pv.z, pd);
        pd = fmaf(Cf[mt][3], pv.w, pd);
    }
    pm += __shfl_xor(pm, 16); pm += __shfl_xor(pm, 32);   // ||mx||^2
    pd += __shfl_xor(pd, 16); pd += __shfl_xor(pd, 32);   // <mx, p>
    float xn2 = xn2s[w * 16 + c];

    float xn      = fmaxf(sqrtf(xn2), MINN);
    float mxn_raw = sqrtf(pm);
    float mxn     = fmaxf(mxn_raw, MINN);
    float alpha   = tanhf(mxn / xn * artanh_(xn)) / mxn;
    if (mxn_raw <= 1e-10f) alpha = 0.f;     // zero-row guard

    float x2  = alpha * alpha * pm;
    float xy  = alpha * pd;
    float den = fmaxf(fmaf(x2, y2, 1.f + 2.f * xy), MINN);
    float ca  = (1.f + 2.f * xy + y2) * alpha / den;
    float cb  = (1.f - x2) / den;

    // ||h||^2 analytically: h = ca*mx + cb*p
    float hn2 = ca * ca * pm + 2.f * ca * cb * pd + cb * cb * y2;
    float hn  = fmaxf(sqrtf(hn2), MINN);
    float lsc = artanh_(hn) / hn;
    float s1  = lsc * ca, s2 = lsc * cb;

    // ---- pack to fp16 via LDS transpose (overlay own wave's dead x region)
    uint2* lout = (uint2*)((char*)xs + (size_t)w * 16 * 136 * 2);
#pragma unroll
    for (int mt = 0; mt < 8; ++mt) {
        float4 pv = ps4[mt * 4 + g];
        H4 u;
        u.h[0] = (_Float16)fmaf(s1, Cf[mt][0], s2 * pv.x);
        u.h[1] = (_Float16)fmaf(s1, Cf[mt][1], s2 * pv.y);
        u.h[2] = (_Float16)fmaf(s1, Cf[mt][2], s2 * pv.z);
        u.h[3] = (_Float16)fmaf(s1, Cf[mt][3], s2 * pv.w);
        lout[c * 33 + mt * 4 + g] = u.u2;   // col = mt*4+g holds dims 4col..4col+3
    }
    __syncthreads();

    // ---- coalesced copy-out
    for (int it = 0; it < 8; ++it) {
        int lin  = it * BLK + t;        // 2048 uint2
        int node = lin >> 5;
        int col  = lin & 31;
        int gn   = node0 + node;
        if (gn < N) {
            const uint2* lsrc = (const uint2*)((const char*)xs + (size_t)(node >> 4) * 4352);
            ht[(size_t)gn * 32 + col] = lsrc[(node & 15) * 33 + col];
        }
    }
}

// ---------------------------------------------------------------------------
// CSR build: memset -> hist -> scan(3) -> scatter
// ---------------------------------------------------------------------------
__global__ void k_hist(const int* __restrict__ ei, int* __restrict__ cnt, int E) {
    int e = blockIdx.x * 256 + threadIdx.x;
    if (e < E) atomicAdd(&cnt[ei[E + e]], 1);
}

__global__ __launch_bounds__(256) void k_scan1(
    const int* __restrict__ cnt, int* __restrict__ ptr,
    int* __restrict__ part, int N)
{
    __shared__ int s[256];
    int t = threadIdx.x;
    int base = blockIdx.x * 1024 + t * 4;
    int v0 = 0, v1 = 0, v2 = 0, v3 = 0;
    if (base + 3 < N) {
        int4 q = *(const int4*)&cnt[base];
        v0 = q.x; v1 = q.y; v2 = q.z; v3 = q.w;
    } else {
        if (base + 0 < N) v0 = cnt[base + 0];
        if (base + 1 < N) v1 = cnt[base + 1];
        if (base + 2 < N) v2 = cnt[base + 2];
        if (base + 3 < N) v3 = cnt[base + 3];
    }
    int sum = v0 + v1 + v2 + v3;
    s[t] = sum;
    __syncthreads();
    for (int off = 1; off < 256; off <<= 1) {
        int xv = (t >= off) ? s[t - off] : 0;
        __syncthreads();
        s[t] += xv;
        __syncthreads();
    }
    int excl = s[t] - sum;
    if (t == 255) part[blockIdx.x] = s[255];
    int r = excl;
    if (base + 0 < N) ptr[base + 0] = r; r += v0;
    if (base + 1 < N) ptr[base + 1] = r; r += v1;
    if (base + 2 < N) ptr[base + 2] = r; r += v2;
    if (base + 3 < N) ptr[base + 3] = r;
}

__global__ __launch_bounds__(256) void k_scan2(int* __restrict__ part, int nc) {
    __shared__ int s[256];
    int t = threadIdx.x;
    int v = (t < nc) ? part[t] : 0;
    s[t] = v;
    __syncthreads();
    for (int off = 1; off < 256; off <<= 1) {
        int xv = (t >= off) ? s[t - off] : 0;
        __syncthreads();
        s[t] += xv;
        __syncthreads();
    }
    if (t < nc) part[t] = s[t] - v;   // exclusive
}

__global__ void k_scan3(int* __restrict__ ptr, const int* __restrict__ part, int N) {
    int i = blockIdx.x * 256 + threadIdx.x;
    if (i < N) ptr[i] += part[i >> 10];
}

__global__ void k_scatter(const int* __restrict__ ei, const float* __restrict__ ew,
                          int* __restrict__ ptr, int2* __restrict__ sorted, int E)
{
    int e = blockIdx.x * 256 + threadIdx.x;
    if (e >= E) return;
    int src = ei[e];
    int dst = ei[E + e];
    float w = ew[e];
    int pos = atomicAdd(&ptr[dst], 1);
    sorted[pos] = make_int2(src, __float_as_int(w));
}

// ---------------------------------------------------------------------------
// Fused aggregation + epilogue: ONE NODE PER WAVE64.
// start/end/descriptors are wave-uniform -> scalar loads, no shuffles.
// Lane owns dims {2*lane, 2*lane+1} (one half2 = 4B per row).
// ---------------------------------------------------------------------------
__global__ __launch_bounds__(256) void k_agg_final(
    const unsigned* __restrict__ ht, const int* __restrict__ ptr,
    const int2* __restrict__ sorted, const float* __restrict__ a_in,
    float* __restrict__ out, int N)
{
    const int t    = threadIdx.x;
    const int lane = t & 63;
    const int wv   = t >> 6;
    const int n    = blockIdx.x * 4 + wv;
    if (n >= N) return;
    const float a = a_in[0];

    float2 acc = h2f(ht[(size_t)n * 64 + lane]);   // agg starts at h_t[n]

    int s0 = __builtin_amdgcn_readfirstlane((n > 0) ? ptr[n - 1] : 0);
    int e0 = __builtin_amdgcn_readfirstlane(ptr[n]);

    int j = s0;
    for (; j + 4 <= e0; j += 4) {
        int2 d0 = sorted[j + 0];
        int2 d1 = sorted[j + 1];
        int2 d2 = sorted[j + 2];
        int2 d3 = sorted[j + 3];
        int r0 = __builtin_amdgcn_readfirstlane(d0.x);
        int r1 = __builtin_amdgcn_readfirstlane(d1.x);
        int r2 = __builtin_amdgcn_readfirstlane(d2.x);
        int r3 = __builtin_amdgcn_readfirstlane(d3.x);
        unsigned g0 = ht[(size_t)r0 * 64 + lane];
        unsigned g1 = ht[(size_t)r1 * 64 + lane];
        unsigned g2 = ht[(size_t)r2 * 64 + lane];
        unsigned g3 = ht[(size_t)r3 * 64 + lane];
        float w0 = __int_as_float(d0.y);
        float w1 = __int_as_float(d1.y);
        float w2 = __int_as_float(d2.y);
        float w3 = __int_as_float(d3.y);
        float2 f0 = h2f(g0), f1 = h2f(g1), f2 = h2f(g2), f3 = h2f(g3);
        acc.x = fmaf(w0, f0.x, acc.x); acc.y = fmaf(w0, f0.y, acc.y);
        acc.x = fmaf(w1, f1.x, acc.x); acc.y = fmaf(w1, f1.y, acc.y);
        acc.x = fmaf(w2, f2.x, acc.x); acc.y = fmaf(w2, f2.y, acc.y);
        acc.x = fmaf(w3, f3.x, acc.x); acc.y = fmaf(w3, f3.y, acc.y);
    }
    for (; j < e0; ++j) {
        int2 d = sorted[j];
        int  r = __builtin_amdgcn_readfirstlane(d.x);
        unsigned g = ht[(size_t)r * 64 + lane];
        float wj = __int_as_float(d.y);
        float2 f = h2f(g);
        acc.x = fmaf(wj, f.x, acc.x);
        acc.y = fmaf(wj, f.y, acc.y);
    }

    // epilogue: project(expmap0(prelu(logmap0(expmap0(acc)))))
    float pn  = fmaf(acc.x, acc.x, acc.y * acc.y);
    float n2  = red64(pn);
    float ncl = fmaxf(sqrtf(n2), MINN);
    float tt  = tanhf(ncl);
    float ny  = fmaxf(tt, MINN);
    float sc  = (artanh_(ny) / ny) * (tt / ncl);

    float v0 = sc * acc.x; v0 = (v0 >= 0.f) ? v0 : a * v0;
    float v1 = sc * acc.y; v1 = (v1 >= 0.f) ? v1 : a * v1;

    float pv = fmaf(v0, v0, v1 * v1);
    float m2 = red64(pv);
    float rc = fmaxf(sqrtf(m2), MINN);
    float te = tanhf(rc);
    float es = te / rc;
    float en = fmaxf(te, MINN);
    const float maxn = 1.0f - BALLEPS;
    float fsc = (en > maxn) ? (es * maxn / en) : es;

    ((float2*)out)[(size_t)n * 64 + lane] = make_float2(fsc * v0, fsc * v1);
}

// ---------------------------------------------------------------------------
extern "C" void kernel_launch(void* const* d_in, const int* in_sizes, int n_in,
                              void* d_out, int out_size, void* d_ws, size_t ws_size,
                              hipStream_t stream)
{
    const float* x  = (const float*)d_in[0];
    const int*   ei = (const int*)  d_in[1];
    const float* ew = (const float*)d_in[2];
    const float* W  = (const float*)d_in[3];
    const float* b  = (const float*)d_in[4];
    const float* a  = (const float*)d_in[5];
    float* out = (float*)d_out;

    const int N = in_sizes[0] / D;
    const int E = in_sizes[1] / 2;

    // workspace carve-up (~31.2 MB)
    char* ws = (char*)d_ws;
    size_t HT_B   = (size_t)N * D * 2;          // fp16 h_t
    uint2* ht     = (uint2*)ws;
    int*   cnt    = (int*)(ws + HT_B);
    int*   ptr    = (int*)(ws + HT_B + (size_t)N * 4);
    int*   part   = (int*)(ws + HT_B + (size_t)N * 8);
    int2*  sorted = (int2*)(ws + HT_B + (size_t)N * 8 + 1024);

    int nc = (N + 1023) / 1024;   // scan chunks

    k_node_mfma<<<(N + 63) / 64, BLK, 0, stream>>>(x, W, b, ht, N);

    hipMemsetAsync(cnt, 0, (size_t)N * 4, stream);
    k_hist<<<(E + 255) / 256, 256, 0, stream>>>(ei, cnt, E);
    k_scan1<<<nc, 256, 0, stream>>>(cnt, ptr, part, N);
    k_scan2<<<1, 256, 0, stream>>>(part, nc);
    k_scan3<<<(N + 255) / 256, 256, 0, stream>>>(ptr, part, N);
    k_scatter<<<(E + 255) / 256, 256, 0, stream>>>(ei, ew, ptr, sorted, E);

    k_agg_final<<<(N + 3) / 4, 256, 0, stream>>>((const unsigned*)ht, ptr, sorted, a, out, N);
}

// Round 5
// 228.594 us; speedup vs baseline: 1.1127x; 1.1127x over previous
//
#include <hip/hip_runtime.h>
#include <hip/hip_fp16.h>
#include <cstdint>

#define D 128
#define BLK 256

constexpr float MINN    = 1e-15f;
constexpr float ATCLIP  = 1.0f - 1e-7f;
constexpr float BALLEPS = 4e-3f;

typedef _Float16 f16x8 __attribute__((ext_vector_type(8)));
typedef float    f32x4 __attribute__((ext_vector_type(4)));

union H4 { _Float16 h[4]; uint2 u2; };
union H8 { _Float16 h[8]; uint4 u4; };

__device__ __forceinline__ float red32(float v) {
    v += __shfl_xor(v, 1);
    v += __shfl_xor(v, 2);
    v += __shfl_xor(v, 4);
    v += __shfl_xor(v, 8);
    v += __shfl_xor(v, 16);
    return v;
}

__device__ __forceinline__ float red64(float v) {
    v += __shfl_xor(v, 1, 64);
    v += __shfl_xor(v, 2, 64);
    v += __shfl_xor(v, 4, 64);
    v += __shfl_xor(v, 8, 64);
    v += __shfl_xor(v, 16, 64);
    v += __shfl_xor(v, 32, 64);
    return v;
}

__device__ __forceinline__ float red16(float v) {
    v += __shfl_xor(v, 1, 64);
    v += __shfl_xor(v, 2, 64);
    v += __shfl_xor(v, 4, 64);
    v += __shfl_xor(v, 8, 64);
    return v;
}

// fast transcendentals (args here are small: |x| < ~16)
__device__ __forceinline__ float tanh_fast(float x) {   // x >= 0
    float e = __expf(2.f * fminf(x, 15.f));
    return __fdividef(e - 1.f, e + 1.f);
}
__device__ __forceinline__ float artanh_fast(float x) { // x in [0, 1)
    x = fminf(x, ATCLIP);
    return 0.5f * __logf(__fdividef(1.f + x, 1.f - x));
}

// ---------------------------------------------------------------------------
// Kernel 1 (MFMA): h_t = logmap0( mobius_add( mobius_matvec(W,x), expmap0(b) ) )
// 64 nodes/block, 4 waves. Also computes the in-degree histogram for a slice
// of edges (independent work, overlaps staging/MFMA).
// ht written fp16: row = 256 B, dims 8q..8q+7 at byte offset q*16.
// ---------------------------------------------------------------------------
__global__ __launch_bounds__(BLK) void k_node_mfma(
    const float* __restrict__ x, const float* __restrict__ W,
    const float* __restrict__ b, uint2* __restrict__ ht, int N,
    const int* __restrict__ ei, int* __restrict__ cnt, int E, int eslice)
{
    __shared__ _Float16 Ws[D * 136];    // 34816 B, row-major padded
    __shared__ _Float16 xs[64 * 136];   // 17408 B (later overlaid by out-staging)
    __shared__ float    ps[D];          // p = expmap0(b)
    __shared__ float    xn2s[64];       // exact fp32 ||x||^2 per node

    const int t     = threadIdx.x;
    const int node0 = blockIdx.x * 64;

    // ---- fused in-degree histogram (slice of edges; global-only, no sync dep)
    {
        int e0 = blockIdx.x * eslice;
        for (int i = t; i < eslice; i += BLK) {
            int e = e0 + i;
            if (e < E) atomicAdd(&cnt[ei[E + e]], 1);
        }
    }

    // ---- stage W fp32 -> fp16 LDS
    for (int it = 0; it < 16; ++it) {
        int lin = it * BLK + t;         // 4096 float4
        int row = lin >> 5;
        int c4  = (lin & 31) * 4;
        float4 v = ((const float4*)W)[lin];
        H4 u;
        u.h[0] = (_Float16)v.x; u.h[1] = (_Float16)v.y;
        u.h[2] = (_Float16)v.z; u.h[3] = (_Float16)v.w;
        *(uint2*)&Ws[row * 136 + c4] = u.u2;
    }

    // ---- stage x fp32 -> fp16 LDS + exact fp32 norms
    for (int it = 0; it < 8; ++it) {
        int lin  = it * BLK + t;        // 2048 float4
        int node = lin >> 5;
        int c4   = (lin & 31) * 4;
        int gn   = node0 + node;
        float4 v = make_float4(0.f, 0.f, 0.f, 0.f);
        if (gn < N) v = ((const float4*)x)[(size_t)gn * 32 + (lin & 31)];
        H4 u;
        u.h[0] = (_Float16)v.x; u.h[1] = (_Float16)v.y;
        u.h[2] = (_Float16)v.z; u.h[3] = (_Float16)v.w;
        *(uint2*)&xs[node * 136 + c4] = u.u2;
        float s = fmaf(v.x, v.x, fmaf(v.y, v.y, fmaf(v.z, v.z, v.w * v.w)));
        s = red32(s);                   // sums the 32-lane subgroup = one node
        if ((t & 31) == 0) xn2s[node] = s;
    }

    // ---- p = expmap0(b): wave-wide reduction (replaces 128-iter serial loop)
    {
        float2 b2 = ((const float2*)b)[t & 63];   // 64 lanes x 2 = all 128 dims
        float pb  = fmaf(b2.x, b2.x, b2.y * b2.y);
        float bn2 = red64(pb);
        float bnc    = fmaxf(sqrtf(bn2), MINN);
        float bscale = __fdividef(tanh_fast(bnc), bnc);
        if (t < D) ps[t] = b[t] * bscale;
        xn2s[0] = xn2s[0];  // no-op keep
        // stash ||p||^2 per-thread (uniform across block)
        // recomputed below as y2
        __syncthreads();
        // fallthrough with y2 in register
        // (scope trick: recompute cheaply)
        // ---- MFMA below
        const int lane = t & 63;
        const int w    = t >> 6;
        const int c    = lane & 15;
        const int g    = lane >> 4;
        const float y2 = bscale * bscale * bn2;   // ||p||^2

        f32x4 Cf[8];
#pragma unroll
        for (int mt = 0; mt < 8; ++mt) Cf[mt] = (f32x4){0.f, 0.f, 0.f, 0.f};

        const _Float16* xbase = &xs[(w * 16 + c) * 136];
#pragma unroll
        for (int s = 0; s < 4; ++s) {
            f16x8 Bf = *(const f16x8*)&xbase[s * 32 + g * 8];
#pragma unroll
            for (int mt = 0; mt < 8; ++mt) {
                f16x8 Af = *(const f16x8*)&Ws[(mt * 16 + c) * 136 + s * 32 + g * 8];
                Cf[mt] = __builtin_amdgcn_mfma_f32_16x16x32_f16(Af, Bf, Cf[mt], 0, 0, 0);
            }
        }
        // lane holds mx[mt*16 + g*4 + r][node0 + w*16 + c] in Cf[mt][r]

        // ---- per-node epilogue (node = w*16 + c; 4 lanes per node via quads)
        float pm = 0.f, pd = 0.f;
        const float4* ps4 = (const float4*)ps;
#pragma unroll
        for (int mt = 0; mt < 8; ++mt) {
            float4 pv = ps4[mt * 4 + g];
            pm = fmaf(Cf[mt][0], Cf[mt][0], pm);
            pm = fmaf(Cf[mt][1], Cf[mt][1], pm);
            pm = fmaf(Cf[mt][2], Cf[mt][2], pm);
            pm = fmaf(Cf[mt][3], Cf[mt][3], pm);
            pd = fmaf(Cf[mt][0], pv.x, pd);
            pd = fmaf(Cf[mt][1], pv.y, pd);
            pd = fmaf(Cf[mt][2], pv.z, pd);
            pd = fmaf(Cf[mt][3], pv.w, pd);
        }
        pm += __shfl_xor(pm, 16); pm += __shfl_xor(pm, 32);   // ||mx||^2
        pd += __shfl_xor(pd, 16); pd += __shfl_xor(pd, 32);   // <mx, p>
        float xn2 = xn2s[w * 16 + c];

        float xn      = fmaxf(sqrtf(xn2), MINN);
        float mxn_raw = sqrtf(pm);
        float mxn     = fmaxf(mxn_raw, MINN);
        float alpha   = __fdividef(tanh_fast(__fdividef(mxn, xn) * artanh_fast(xn)), mxn);
        if (mxn_raw <= 1e-10f) alpha = 0.f;     // zero-row guard

        float x2  = alpha * alpha * pm;
        float xy  = alpha * pd;
        float den = fmaxf(fmaf(x2, y2, 1.f + 2.f * xy), MINN);
        float ca  = __fdividef((1.f + 2.f * xy + y2) * alpha, den);
        float cb  = __fdividef(1.f - x2, den);

        // ||h||^2 analytically: h = ca*mx + cb*p
        float hn2 = ca * ca * pm + 2.f * ca * cb * pd + cb * cb * y2;
        float hn  = fmaxf(sqrtf(hn2), MINN);
        float lsc = __fdividef(artanh_fast(hn), hn);
        float s1  = lsc * ca, s2 = lsc * cb;

        // ---- pack to fp16 via LDS transpose (overlay own wave's dead x region)
        uint2* lout = (uint2*)((char*)xs + (size_t)w * 16 * 136 * 2);
#pragma unroll
        for (int mt = 0; mt < 8; ++mt) {
            float4 pv = ps4[mt * 4 + g];
            H4 u;
            u.h[0] = (_Float16)fmaf(s1, Cf[mt][0], s2 * pv.x);
            u.h[1] = (_Float16)fmaf(s1, Cf[mt][1], s2 * pv.y);
            u.h[2] = (_Float16)fmaf(s1, Cf[mt][2], s2 * pv.z);
            u.h[3] = (_Float16)fmaf(s1, Cf[mt][3], s2 * pv.w);
            lout[c * 33 + mt * 4 + g] = u.u2;   // col = mt*4+g holds dims 4col..4col+3
        }
    }
    __syncthreads();

    // ---- coalesced copy-out
    for (int it = 0; it < 8; ++it) {
        int lin  = it * BLK + t;        // 2048 uint2
        int node = lin >> 5;
        int col  = lin & 31;
        int gn   = node0 + node;
        if (gn < N) {
            const uint2* lsrc = (const uint2*)((const char*)xs + (size_t)(node >> 4) * 4352);
            ht[(size_t)gn * 32 + col] = lsrc[(node & 15) * 33 + col];
        }
    }
}

// ---------------------------------------------------------------------------
// CSR build: memset -> (hist fused in k_node) -> scan1 -> scan2 -> scatter(+scan3)
// ---------------------------------------------------------------------------
__global__ __launch_bounds__(256) void k_scan1(
    const int* __restrict__ cnt, int* __restrict__ ptr,
    int* __restrict__ part, int N)
{
    __shared__ int s[256];
    int t = threadIdx.x;
    int base = blockIdx.x * 1024 + t * 4;
    int v0 = 0, v1 = 0, v2 = 0, v3 = 0;
    if (base + 3 < N) {
        int4 q = *(const int4*)&cnt[base];
        v0 = q.x; v1 = q.y; v2 = q.z; v3 = q.w;
    } else {
        if (base + 0 < N) v0 = cnt[base + 0];
        if (base + 1 < N) v1 = cnt[base + 1];
        if (base + 2 < N) v2 = cnt[base + 2];
        if (base + 3 < N) v3 = cnt[base + 3];
    }
    int sum = v0 + v1 + v2 + v3;
    s[t] = sum;
    __syncthreads();
    for (int off = 1; off < 256; off <<= 1) {
        int xv = (t >= off) ? s[t - off] : 0;
        __syncthreads();
        s[t] += xv;
        __syncthreads();
    }
    int excl = s[t] - sum;
    if (t == 255) part[blockIdx.x] = s[255];
    int r = excl;
    if (base + 0 < N) ptr[base + 0] = r; r += v0;
    if (base + 1 < N) ptr[base + 1] = r; r += v1;
    if (base + 2 < N) ptr[base + 2] = r; r += v2;
    if (base + 3 < N) ptr[base + 3] = r;
}

__global__ __launch_bounds__(256) void k_scan2(int* __restrict__ part, int nc) {
    __shared__ int s[256];
    int t = threadIdx.x;
    int v = (t < nc) ? part[t] : 0;
    s[t] = v;
    __syncthreads();
    for (int off = 1; off < 256; off <<= 1) {
        int xv = (t >= off) ? s[t - off] : 0;
        __syncthreads();
        s[t] += xv;
        __syncthreads();
    }
    if (t < nc) part[t] = s[t] - v;   // exclusive
}

// scatter with chunk-offset add folded in (replaces k_scan3).
// sorted[pos] = (src byte-offset into ht, weight bits)
__global__ void k_scatter(const int* __restrict__ ei, const float* __restrict__ ew,
                          int* __restrict__ ptr, const int* __restrict__ part,
                          int2* __restrict__ sorted, int E)
{
    int e = blockIdx.x * 256 + threadIdx.x;
    if (e >= E) return;
    int src = ei[e];
    int dst = ei[E + e];
    float w = ew[e];
    int pos = atomicAdd(&ptr[dst], 1) + part[dst >> 10];
    sorted[pos] = make_int2(src << 8, __float_as_int(w));
}

// ---------------------------------------------------------------------------
// Fused aggregation + epilogue: 16 lanes per node (4 nodes per wave64).
// Lane owns dims 8*li .. 8*li+7 (uint4 = 16 B per gathered row).
// h2_t = logmap0(expmap0(agg)) == agg (identity within fp32 tolerance).
// ---------------------------------------------------------------------------
__global__ __launch_bounds__(256) void k_agg_final(
    const char* __restrict__ htb, const int* __restrict__ ptr,
    const int* __restrict__ part, const int2* __restrict__ sorted,
    const float* __restrict__ a_in, float* __restrict__ out, int N)
{
    const int t   = threadIdx.x;
    const int li  = t & 15;          // lane within 16-lane group
    const int grp = t >> 4;          // group within block (0..15)
    const int n   = blockIdx.x * 16 + grp;
    if (n >= N) return;
    const float a = a_in[0];

    // own row (agg starts at h_t[n])
    H8 own; own.u4 = *(const uint4*)(htb + (size_t)n * 256 + li * 16);
    float acc[8];
#pragma unroll
    for (int k = 0; k < 8; ++k) acc[k] = (float)own.h[k];

    int s0 = (n > 0) ? (ptr[n - 1] + part[(n - 1) >> 10]) : 0;
    int e0 = ptr[n] + part[n >> 10];

    const int lioff = li * 16;
    int j = s0;
    for (; j + 2 <= e0; j += 2) {
        int2 d0 = sorted[j];
        int2 d1 = sorted[j + 1];
        H8 g0, g1;
        g0.u4 = *(const uint4*)(htb + (unsigned)d0.x + lioff);
        g1.u4 = *(const uint4*)(htb + (unsigned)d1.x + lioff);
        float w0 = __int_as_float(d0.y);
        float w1 = __int_as_float(d1.y);
#pragma unroll
        for (int k = 0; k < 8; ++k) acc[k] = fmaf((float)g0.h[k], w0, acc[k]);
#pragma unroll
        for (int k = 0; k < 8; ++k) acc[k] = fmaf((float)g1.h[k], w1, acc[k]);
    }
    if (j < e0) {
        int2 d = sorted[j];
        H8 g; g.u4 = *(const uint4*)(htb + (unsigned)d.x + lioff);
        float w = __int_as_float(d.y);
#pragma unroll
        for (int k = 0; k < 8; ++k) acc[k] = fmaf((float)g.h[k], w, acc[k]);
    }

    // h2_t = acc; PReLU
    float pv = 0.f;
#pragma unroll
    for (int k = 0; k < 8; ++k) {
        float v = acc[k];
        v = (v >= 0.f) ? v : a * v;
        acc[k] = v;
        pv = fmaf(v, v, pv);
    }
    float m2 = red16(pv);
    float rc = fmaxf(sqrtf(m2), MINN);
    float te = tanh_fast(rc);
    // project(expmap0): scale = min(tanh(rc), maxnorm) / rc
    const float maxn = 1.0f - BALLEPS;
    float fsc = __fdividef(fminf(fmaxf(te, MINN), maxn), rc);

    float4 o0 = make_float4(fsc * acc[0], fsc * acc[1], fsc * acc[2], fsc * acc[3]);
    float4 o1 = make_float4(fsc * acc[4], fsc * acc[5], fsc * acc[6], fsc * acc[7]);
    float4* orow = (float4*)(out + (size_t)n * D);
    orow[li * 2 + 0] = o0;
    orow[li * 2 + 1] = o1;
}

// ---------------------------------------------------------------------------
extern "C" void kernel_launch(void* const* d_in, const int* in_sizes, int n_in,
                              void* d_out, int out_size, void* d_ws, size_t ws_size,
                              hipStream_t stream)
{
    const float* x  = (const float*)d_in[0];
    const int*   ei = (const int*)  d_in[1];
    const float* ew = (const float*)d_in[2];
    const float* W  = (const float*)d_in[3];
    const float* b  = (const float*)d_in[4];
    const float* a  = (const float*)d_in[5];
    float* out = (float*)d_out;

    const int N = in_sizes[0] / D;
    const int E = in_sizes[1] / 2;

    // workspace carve-up (~31.2 MB)
    char* ws = (char*)d_ws;
    size_t HT_B   = (size_t)N * D * 2;          // fp16 h_t
    uint2* ht     = (uint2*)ws;
    int*   cnt    = (int*)(ws + HT_B);
    int*   ptr    = (int*)(ws + HT_B + (size_t)N * 4);
    int*   part   = (int*)(ws + HT_B + (size_t)N * 8);
    int2*  sorted = (int2*)(ws + HT_B + (size_t)N * 8 + 1024);

    int nc  = (N + 1023) / 1024;    // scan chunks
    int nb1 = (N + 63) / 64;        // k_node blocks
    int eslice = (E + nb1 - 1) / nb1;

    hipMemsetAsync(cnt, 0, (size_t)N * 4, stream);
    k_node_mfma<<<nb1, BLK, 0, stream>>>(x, W, b, ht, N, ei, cnt, E, eslice);
    k_scan1<<<nc, 256, 0, stream>>>(cnt, ptr, part, N);
    k_scan2<<<1, 256, 0, stream>>>(part, nc);
    k_scatter<<<(E + 255) / 256, 256, 0, stream>>>(ei, ew, ptr, part, sorted, E);
    k_agg_final<<<(N + 15) / 16, 256, 0, stream>>>((const char*)ht, ptr, part, sorted, a, out, N);
}

// Round 6
// 220.871 us; speedup vs baseline: 1.1516x; 1.0350x over previous
//
#include <hip/hip_runtime.h>
#include <hip/hip_fp16.h>
#include <cstdint>

#define D 128
#define BLK 256

constexpr float MINN    = 1e-15f;
constexpr float ATCLIP  = 1.0f - 1e-7f;
constexpr float BALLEPS = 4e-3f;

typedef _Float16 f16x8 __attribute__((ext_vector_type(8)));
typedef float    f32x4 __attribute__((ext_vector_type(4)));

union H4 { _Float16 h[4]; uint2 u2; };
union H8 { _Float16 h[8]; uint4 u4; };

__device__ __forceinline__ float red32(float v) {
    v += __shfl_xor(v, 1);
    v += __shfl_xor(v, 2);
    v += __shfl_xor(v, 4);
    v += __shfl_xor(v, 8);
    v += __shfl_xor(v, 16);
    return v;
}

__device__ __forceinline__ float red64(float v) {
    v += __shfl_xor(v, 1, 64);
    v += __shfl_xor(v, 2, 64);
    v += __shfl_xor(v, 4, 64);
    v += __shfl_xor(v, 8, 64);
    v += __shfl_xor(v, 16, 64);
    v += __shfl_xor(v, 32, 64);
    return v;
}

__device__ __forceinline__ float red16(float v) {
    v += __shfl_xor(v, 1, 64);
    v += __shfl_xor(v, 2, 64);
    v += __shfl_xor(v, 4, 64);
    v += __shfl_xor(v, 8, 64);
    return v;
}

// fast transcendentals (args here are small: |x| < ~16)
__device__ __forceinline__ float tanh_fast(float x) {   // x >= 0
    float e = __expf(2.f * fminf(x, 15.f));
    return __fdividef(e - 1.f, e + 1.f);
}
__device__ __forceinline__ float artanh_fast(float x) { // x in [0, 1)
    x = fminf(x, ATCLIP);
    return 0.5f * __logf(__fdividef(1.f + x, 1.f - x));
}

// ---------------------------------------------------------------------------
// Kernel 0: W fp32 -> fp16, fragment-order layout.
// Wh[f*1024 + r*8 + j] = (fp16) W[r][f*8+j],  f = k-chunk 0..15, r = row 0..127.
// A-frag for (s,g,mt,c) is then 16 contiguous bytes at ((s*4+g)*1024+(mt*16+c)*8).
// ---------------------------------------------------------------------------
__global__ void k_wcvt(const float* __restrict__ W, _Float16* __restrict__ Wh) {
    int i = blockIdx.x * 256 + threadIdx.x;   // 0..2047
    if (i >= 2048) return;
    int f = i >> 7;
    int r = i & 127;
    const float4* src = (const float4*)(W + r * 128 + f * 8);
    float4 v0 = src[0], v1 = src[1];
    H8 u;
    u.h[0] = (_Float16)v0.x; u.h[1] = (_Float16)v0.y;
    u.h[2] = (_Float16)v0.z; u.h[3] = (_Float16)v0.w;
    u.h[4] = (_Float16)v1.x; u.h[5] = (_Float16)v1.y;
    u.h[6] = (_Float16)v1.z; u.h[7] = (_Float16)v1.w;
    *(uint4*)(Wh + i * 8) = u.u4;
}

// ---------------------------------------------------------------------------
// Kernel 1 (MFMA): h_t = logmap0( mobius_add( mobius_matvec(W,x), expmap0(b) ) )
// 64 nodes/block, 4 waves. W fragments read straight from global (L1-resident).
// Fused in-degree histogram for a slice of edges.
// ht written fp16: row = 256 B.
// ---------------------------------------------------------------------------
__global__ __launch_bounds__(BLK) void k_node_mfma(
    const float* __restrict__ x, const _Float16* __restrict__ Wh,
    const float* __restrict__ b, uint2* __restrict__ ht, int N,
    const int* __restrict__ ei, int* __restrict__ cnt, int E, int eslice)
{
    __shared__ _Float16 xs[64 * 136];   // 17408 B (later overlaid by out-staging)
    __shared__ float    ps[D];          // p = expmap0(b)
    __shared__ float    xn2s[64];       // exact fp32 ||x||^2 per node

    const int t     = threadIdx.x;
    const int node0 = blockIdx.x * 64;

    // ---- fused in-degree histogram (slice of edges; global-only, no sync dep)
    {
        int e0 = blockIdx.x * eslice;
        for (int i = t; i < eslice; i += BLK) {
            int e = e0 + i;
            if (e < E) atomicAdd(&cnt[ei[E + e]], 1);
        }
    }

    // ---- stage x fp32 -> fp16 LDS + exact fp32 norms
    for (int it = 0; it < 8; ++it) {
        int lin  = it * BLK + t;        // 2048 float4
        int node = lin >> 5;
        int c4   = (lin & 31) * 4;
        int gn   = node0 + node;
        float4 v = make_float4(0.f, 0.f, 0.f, 0.f);
        if (gn < N) v = ((const float4*)x)[(size_t)gn * 32 + (lin & 31)];
        H4 u;
        u.h[0] = (_Float16)v.x; u.h[1] = (_Float16)v.y;
        u.h[2] = (_Float16)v.z; u.h[3] = (_Float16)v.w;
        *(uint2*)&xs[node * 136 + c4] = u.u2;
        float s = fmaf(v.x, v.x, fmaf(v.y, v.y, fmaf(v.z, v.z, v.w * v.w)));
        s = red32(s);                   // sums the 32-lane subgroup = one node
        if ((t & 31) == 0) xn2s[node] = s;
    }

    // ---- p = expmap0(b): wave-wide reduction
    float2 b2 = ((const float2*)b)[t & 63];   // 64 lanes x 2 = all 128 dims
    float pb  = fmaf(b2.x, b2.x, b2.y * b2.y);
    float bn2 = red64(pb);
    float bnc    = fmaxf(sqrtf(bn2), MINN);
    float bscale = __fdividef(tanh_fast(bnc), bnc);
    if (t < D) ps[t] = b[t] * bscale;
    const float y2 = bscale * bscale * bn2;   // ||p||^2
    __syncthreads();

    // ---- MFMA: mx[128 out][16 nodes] per wave
    const int lane = t & 63;
    const int w    = t >> 6;
    const int c    = lane & 15;     // node within wave-tile / W row within m-tile
    const int g    = lane >> 4;     // quad

    f32x4 Cf[8];
#pragma unroll
    for (int mt = 0; mt < 8; ++mt) Cf[mt] = (f32x4){0.f, 0.f, 0.f, 0.f};

    const _Float16* xbase = &xs[(w * 16 + c) * 136];
#pragma unroll
    for (int s = 0; s < 4; ++s) {
        f16x8 Bf = *(const f16x8*)&xbase[s * 32 + g * 8];
        const _Float16* wp = Wh + ((s * 4 + g) << 10) + (c << 3);
#pragma unroll
        for (int mt = 0; mt < 8; ++mt) {
            f16x8 Af = *(const f16x8*)&wp[mt << 7];
            Cf[mt] = __builtin_amdgcn_mfma_f32_16x16x32_f16(Af, Bf, Cf[mt], 0, 0, 0);
        }
    }
    // lane holds mx[mt*16 + g*4 + r][node0 + w*16 + c] in Cf[mt][r]

    // ---- per-node epilogue (node = w*16 + c; 4 lanes per node via quads)
    float pm = 0.f, pd = 0.f;
    const float4* ps4 = (const float4*)ps;
#pragma unroll
    for (int mt = 0; mt < 8; ++mt) {
        float4 pv = ps4[mt * 4 + g];
        pm = fmaf(Cf[mt][0], Cf[mt][0], pm);
        pm = fmaf(Cf[mt][1], Cf[mt][1], pm);
        pm = fmaf(Cf[mt][2], Cf[mt][2], pm);
        pm = fmaf(Cf[mt][3], Cf[mt][3], pm);
        pd = fmaf(Cf[mt][0], pv.x, pd);
        pd = fmaf(Cf[mt][1], pv.y, pd);
        pd = fmaf(Cf[mt][2], pv.z, pd);
        pd = fmaf(Cf[mt][3], pv.w, pd);
    }
    pm += __shfl_xor(pm, 16); pm += __shfl_xor(pm, 32);   // ||mx||^2
    pd += __shfl_xor(pd, 16); pd += __shfl_xor(pd, 32);   // <mx, p>
    float xn2 = xn2s[w * 16 + c];

    float xn      = fmaxf(sqrtf(xn2), MINN);
    float mxn_raw = sqrtf(pm);
    float mxn     = fmaxf(mxn_raw, MINN);
    float alpha   = __fdividef(tanh_fast(__fdividef(mxn, xn) * artanh_fast(xn)), mxn);
    if (mxn_raw <= 1e-10f) alpha = 0.f;     // zero-row guard

    float x2  = alpha * alpha * pm;
    float xy  = alpha * pd;
    float den = fmaxf(fmaf(x2, y2, 1.f + 2.f * xy), MINN);
    float ca  = __fdividef((1.f + 2.f * xy + y2) * alpha, den);
    float cb  = __fdividef(1.f - x2, den);

    // ||h||^2 analytically: h = ca*mx + cb*p
    float hn2 = ca * ca * pm + 2.f * ca * cb * pd + cb * cb * y2;
    float hn  = fmaxf(sqrtf(hn2), MINN);
    float lsc = __fdividef(artanh_fast(hn), hn);
    float s1  = lsc * ca, s2 = lsc * cb;

    // ---- pack to fp16 via LDS transpose (overlay own wave's dead x region)
    uint2* lout = (uint2*)((char*)xs + (size_t)w * 16 * 136 * 2);
#pragma unroll
    for (int mt = 0; mt < 8; ++mt) {
        float4 pv = ps4[mt * 4 + g];
        H4 u;
        u.h[0] = (_Float16)fmaf(s1, Cf[mt][0], s2 * pv.x);
        u.h[1] = (_Float16)fmaf(s1, Cf[mt][1], s2 * pv.y);
        u.h[2] = (_Float16)fmaf(s1, Cf[mt][2], s2 * pv.z);
        u.h[3] = (_Float16)fmaf(s1, Cf[mt][3], s2 * pv.w);
        lout[c * 33 + mt * 4 + g] = u.u2;   // col = mt*4+g holds dims 4col..4col+3
    }
    __syncthreads();

    // ---- coalesced copy-out
    for (int it = 0; it < 8; ++it) {
        int lin  = it * BLK + t;        // 2048 uint2
        int node = lin >> 5;
        int col  = lin & 31;
        int gn   = node0 + node;
        if (gn < N) {
            const uint2* lsrc = (const uint2*)((const char*)xs + (size_t)(node >> 4) * 4352);
            ht[(size_t)gn * 32 + col] = lsrc[(node & 15) * 33 + col];
        }
    }
}

// ---------------------------------------------------------------------------
// CSR build: memset -> (hist fused in k_node) -> scan1 -> scan2 -> scatter(+scan3)
// ---------------------------------------------------------------------------
__global__ __launch_bounds__(256) void k_scan1(
    const int* __restrict__ cnt, int* __restrict__ ptr,
    int* __restrict__ part, int N)
{
    __shared__ int s[256];
    int t = threadIdx.x;
    int base = blockIdx.x * 1024 + t * 4;
    int v0 = 0, v1 = 0, v2 = 0, v3 = 0;
    if (base + 3 < N) {
        int4 q = *(const int4*)&cnt[base];
        v0 = q.x; v1 = q.y; v2 = q.z; v3 = q.w;
    } else {
        if (base + 0 < N) v0 = cnt[base + 0];
        if (base + 1 < N) v1 = cnt[base + 1];
        if (base + 2 < N) v2 = cnt[base + 2];
        if (base + 3 < N) v3 = cnt[base + 3];
    }
    int sum = v0 + v1 + v2 + v3;
    s[t] = sum;
    __syncthreads();
    for (int off = 1; off < 256; off <<= 1) {
        int xv = (t >= off) ? s[t - off] : 0;
        __syncthreads();
        s[t] += xv;
        __syncthreads();
    }
    int excl = s[t] - sum;
    if (t == 255) part[blockIdx.x] = s[255];
    int r = excl;
    if (base + 0 < N) ptr[base + 0] = r; r += v0;
    if (base + 1 < N) ptr[base + 1] = r; r += v1;
    if (base + 2 < N) ptr[base + 2] = r; r += v2;
    if (base + 3 < N) ptr[base + 3] = r;
}

__global__ __launch_bounds__(256) void k_scan2(int* __restrict__ part, int nc) {
    __shared__ int s[256];
    int t = threadIdx.x;
    int v = (t < nc) ? part[t] : 0;
    s[t] = v;
    __syncthreads();
    for (int off = 1; off < 256; off <<= 1) {
        int xv = (t >= off) ? s[t - off] : 0;
        __syncthreads();
        s[t] += xv;
        __syncthreads();
    }
    if (t < nc) part[t] = s[t] - v;   // exclusive
}

// scatter with chunk-offset add folded in.
// sorted[pos] = (src byte-offset into ht, weight bits)
__global__ void k_scatter(const int* __restrict__ ei, const float* __restrict__ ew,
                          int* __restrict__ ptr, const int* __restrict__ part,
                          int2* __restrict__ sorted, int E)
{
    int e = blockIdx.x * 256 + threadIdx.x;
    if (e >= E) return;
    int src = ei[e];
    int dst = ei[E + e];
    float w = ew[e];
    int pos = atomicAdd(&ptr[dst], 1) + part[dst >> 10];
    sorted[pos] = make_int2(src << 8, __float_as_int(w));
}

// ---------------------------------------------------------------------------
// Fused aggregation + epilogue: 16 lanes per node (4 nodes per wave64).
// Lane owns dims 8*li .. 8*li+7 (uint4 = 16 B per gathered row).
// h2_t = logmap0(expmap0(agg)) == agg (identity within fp32 tolerance).
// ---------------------------------------------------------------------------
__global__ __launch_bounds__(256) void k_agg_final(
    const char* __restrict__ htb, const int* __restrict__ ptr,
    const int* __restrict__ part, const int2* __restrict__ sorted,
    const float* __restrict__ a_in, float* __restrict__ out, int N)
{
    const int t   = threadIdx.x;
    const int li  = t & 15;          // lane within 16-lane group
    const int grp = t >> 4;          // group within block (0..15)
    const int n   = blockIdx.x * 16 + grp;
    if (n >= N) return;
    const float a = a_in[0];

    // own row (agg starts at h_t[n])
    H8 own; own.u4 = *(const uint4*)(htb + (size_t)n * 256 + li * 16);
    float acc[8];
#pragma unroll
    for (int k = 0; k < 8; ++k) acc[k] = (float)own.h[k];

    int s0 = (n > 0) ? (ptr[n - 1] + part[(n - 1) >> 10]) : 0;
    int e0 = ptr[n] + part[n >> 10];

    const int lioff = li * 16;
    int j = s0;
    for (; j + 2 <= e0; j += 2) {
        int2 d0 = sorted[j];
        int2 d1 = sorted[j + 1];
        H8 g0, g1;
        g0.u4 = *(const uint4*)(htb + (unsigned)d0.x + lioff);
        g1.u4 = *(const uint4*)(htb + (unsigned)d1.x + lioff);
        float w0 = __int_as_float(d0.y);
        float w1 = __int_as_float(d1.y);
#pragma unroll
        for (int k = 0; k < 8; ++k) acc[k] = fmaf((float)g0.h[k], w0, acc[k]);
#pragma unroll
        for (int k = 0; k < 8; ++k) acc[k] = fmaf((float)g1.h[k], w1, acc[k]);
    }
    if (j < e0) {
        int2 d = sorted[j];
        H8 g; g.u4 = *(const uint4*)(htb + (unsigned)d.x + lioff);
        float w = __int_as_float(d.y);
#pragma unroll
        for (int k = 0; k < 8; ++k) acc[k] = fmaf((float)g.h[k], w, acc[k]);
    }

    // h2_t = acc; PReLU
    float pv = 0.f;
#pragma unroll
    for (int k = 0; k < 8; ++k) {
        float v = acc[k];
        v = (v >= 0.f) ? v : a * v;
        acc[k] = v;
        pv = fmaf(v, v, pv);
    }
    float m2 = red16(pv);
    float rc = fmaxf(sqrtf(m2), MINN);
    float te = tanh_fast(rc);
    // project(expmap0): scale = min(tanh(rc), maxnorm) / rc
    const float maxn = 1.0f - BALLEPS;
    float fsc = __fdividef(fminf(fmaxf(te, MINN), maxn), rc);

    float4 o0 = make_float4(fsc * acc[0], fsc * acc[1], fsc * acc[2], fsc * acc[3]);
    float4 o1 = make_float4(fsc * acc[4], fsc * acc[5], fsc * acc[6], fsc * acc[7]);
    float4* orow = (float4*)(out + (size_t)n * D);
    orow[li * 2 + 0] = o0;
    orow[li * 2 + 1] = o1;
}

// ---------------------------------------------------------------------------
extern "C" void kernel_launch(void* const* d_in, const int* in_sizes, int n_in,
                              void* d_out, int out_size, void* d_ws, size_t ws_size,
                              hipStream_t stream)
{
    const float* x  = (const float*)d_in[0];
    const int*   ei = (const int*)  d_in[1];
    const float* ew = (const float*)d_in[2];
    const float* W  = (const float*)d_in[3];
    const float* b  = (const float*)d_in[4];
    const float* a  = (const float*)d_in[5];
    float* out = (float*)d_out;

    const int N = in_sizes[0] / D;
    const int E = in_sizes[1] / 2;

    // workspace carve-up (~31.25 MB)
    char* ws = (char*)d_ws;
    size_t HT_B    = (size_t)N * D * 2;          // fp16 h_t
    uint2*     ht     = (uint2*)ws;
    int*       cnt    = (int*)(ws + HT_B);
    int*       ptr    = (int*)(ws + HT_B + (size_t)N * 4);
    int*       part   = (int*)(ws + HT_B + (size_t)N * 8);
    int2*      sorted = (int2*)(ws + HT_B + (size_t)N * 8 + 1024);
    _Float16*  Wh     = (_Float16*)(ws + HT_B + (size_t)N * 8 + 1024 + (size_t)E * 8);

    int nc  = (N + 1023) / 1024;    // scan chunks
    int nb1 = (N + 63) / 64;        // k_node blocks
    int eslice = (E + nb1 - 1) / nb1;

    hipMemsetAsync(cnt, 0, (size_t)N * 4, stream);
    k_wcvt<<<8, 256, 0, stream>>>(W, Wh);
    k_node_mfma<<<nb1, BLK, 0, stream>>>(x, Wh, b, ht, N, ei, cnt, E, eslice);
    k_scan1<<<nc, 256, 0, stream>>>(cnt, ptr, part, N);
    k_scan2<<<1, 256, 0, stream>>>(part, nc);
    k_scatter<<<(E + 255) / 256, 256, 0, stream>>>(ei, ew, ptr, part, sorted, E);
    k_agg_final<<<(N + 15) / 16, 256, 0, stream>>>((const char*)ht, ptr, part, sorted, a, out, N);
}

// Round 7
// 218.702 us; speedup vs baseline: 1.1631x; 1.0099x over previous
//
#include <hip/hip_runtime.h>
#include <hip/hip_fp16.h>
#include <cstdint>

#define D 128
#define BLK 256

constexpr float MINN    = 1e-15f;
constexpr float ATCLIP  = 1.0f - 1e-7f;
constexpr float BALLEPS = 4e-3f;

typedef _Float16 f16x8 __attribute__((ext_vector_type(8)));
typedef float    f32x4 __attribute__((ext_vector_type(4)));

union H4 { _Float16 h[4]; uint2 u2; };
union H8 { _Float16 h[8]; uint4 u4; };

typedef __attribute__((address_space(1))) const void gas_v;
typedef __attribute__((address_space(3))) void las_v;

__device__ __forceinline__ float red64(float v) {
    v += __shfl_xor(v, 1, 64);
    v += __shfl_xor(v, 2, 64);
    v += __shfl_xor(v, 4, 64);
    v += __shfl_xor(v, 8, 64);
    v += __shfl_xor(v, 16, 64);
    v += __shfl_xor(v, 32, 64);
    return v;
}

__device__ __forceinline__ float red16(float v) {
    v += __shfl_xor(v, 1, 64);
    v += __shfl_xor(v, 2, 64);
    v += __shfl_xor(v, 4, 64);
    v += __shfl_xor(v, 8, 64);
    return v;
}

// fast transcendentals (args here are small: |x| < ~16)
__device__ __forceinline__ float tanh_fast(float x) {   // x >= 0
    float e = __expf(2.f * fminf(x, 15.f));
    return __fdividef(e - 1.f, e + 1.f);
}
__device__ __forceinline__ float artanh_fast(float x) { // x in [0, 1)
    x = fminf(x, ATCLIP);
    return 0.5f * __logf(__fdividef(1.f + x, 1.f - x));
}

// ---------------------------------------------------------------------------
// Kernel 0: W fp32 -> fp16, fragment-order layout.
// Wh[f*1024 + r*8 + j] = (fp16) W[r][f*8+j],  f = k-chunk 0..15, r = row 0..127.
// ---------------------------------------------------------------------------
__global__ void k_wcvt(const float* __restrict__ W, _Float16* __restrict__ Wh) {
    int i = blockIdx.x * 256 + threadIdx.x;   // 0..2047
    if (i >= 2048) return;
    int f = i >> 7;
    int r = i & 127;
    const float4* src = (const float4*)(W + r * 128 + f * 8);
    float4 v0 = src[0], v1 = src[1];
    H8 u;
    u.h[0] = (_Float16)v0.x; u.h[1] = (_Float16)v0.y;
    u.h[2] = (_Float16)v0.z; u.h[3] = (_Float16)v0.w;
    u.h[4] = (_Float16)v1.x; u.h[5] = (_Float16)v1.y;
    u.h[6] = (_Float16)v1.z; u.h[7] = (_Float16)v1.w;
    *(uint4*)(Wh + i * 8) = u.u4;
}

// ---------------------------------------------------------------------------
// Kernel 1 (MFMA): h_t = logmap0( mobius_add( mobius_matvec(W,x), expmap0(b) ) )
// 64 nodes/block, 4 waves. x staged fp32 via async global_load_lds (width=16)
// with XOR-swizzled 16B chunks: chunk q of node n at LDS slot n*32 + (q^(n&7)).
// W fragments read straight from global (L1-resident, fragment-order Wh).
// Fused in-degree histogram. ht written fp16: row = 256 B.
// ---------------------------------------------------------------------------
__global__ __launch_bounds__(BLK) void k_node_mfma(
    const float* __restrict__ x, const _Float16* __restrict__ Wh,
    const float* __restrict__ b, uint2* __restrict__ ht, int N,
    const int* __restrict__ ei, int* __restrict__ cnt, int E, int eslice)
{
    __shared__ float xs[64 * 128];      // 32768 B fp32, swizzled (overlaid later)
    __shared__ float ps[D];             // p = expmap0(b)

    const int t     = threadIdx.x;
    const int node0 = blockIdx.x * 64;
    const int lane  = t & 63;
    const int w     = t >> 6;

    // ---- async DMA: x -> LDS (8 x 1KB per wave, fire-and-forget)
#pragma unroll
    for (int i = 0; i < 8; ++i) {
        int P      = (w * 8 + i) * 64 + lane;       // LDS chunk slot 0..2047
        int node   = P >> 5;
        int q      = (P & 31) ^ (node & 7);         // swizzle: slot p holds chunk p^(n&7)
        int node_g = min(node0 + node, N - 1);      // clamp OOB tail (stores guarded later)
        const float* src = x + (size_t)node_g * 128 + q * 4;
        char* dst = (char*)xs + (size_t)(w * 8 + i) * 1024;   // wave-uniform base
        __builtin_amdgcn_global_load_lds((gas_v*)src, (las_v*)dst, 16, 0, 0);
    }

    // ---- fused in-degree histogram (overlaps DMA)
    {
        int e0 = blockIdx.x * eslice;
        for (int i = t; i < eslice; i += BLK) {
            int e = e0 + i;
            if (e < E) atomicAdd(&cnt[ei[E + e]], 1);
        }
    }

    // ---- p = expmap0(b): wave-wide reduction
    float2 b2 = ((const float2*)b)[lane];     // 64 lanes x 2 = all 128 dims
    float pb  = fmaf(b2.x, b2.x, b2.y * b2.y);
    float bn2 = red64(pb);
    float bnc    = fmaxf(sqrtf(bn2), MINN);
    float bscale = __fdividef(tanh_fast(bnc), bnc);
    if (t < D) ps[t] = b[t] * bscale;
    const float y2 = bscale * bscale * bn2;   // ||p||^2
    __syncthreads();                          // drains DMA (vmcnt) + ps visible

    // ---- MFMA: mx[128 out][16 nodes] per wave
    const int c = lane & 15;        // node within wave-tile / W row within m-tile
    const int g = lane >> 4;        // quad

    f32x4 Cf[8];
#pragma unroll
    for (int mt = 0; mt < 8; ++mt) Cf[mt] = (f32x4){0.f, 0.f, 0.f, 0.f};

    const int bnode = w * 16 + c;
    const int sw    = bnode & 7;
    const float* xrow = &xs[bnode * 128];
    float px = 0.f;                 // fp32 ||x||^2 partial (this lane's 32 dims)

#pragma unroll
    for (int s = 0; s < 4; ++s) {
        int q0 = s * 8 + g * 2;
        f32x4 lo = *(const f32x4*)&xrow[(q0 ^ sw) * 4];
        f32x4 hi = *(const f32x4*)&xrow[((q0 + 1) ^ sw) * 4];
        px = fmaf(lo[0], lo[0], px); px = fmaf(lo[1], lo[1], px);
        px = fmaf(lo[2], lo[2], px); px = fmaf(lo[3], lo[3], px);
        px = fmaf(hi[0], hi[0], px); px = fmaf(hi[1], hi[1], px);
        px = fmaf(hi[2], hi[2], px); px = fmaf(hi[3], hi[3], px);
        f16x8 Bf;
        Bf[0] = (_Float16)lo[0]; Bf[1] = (_Float16)lo[1];
        Bf[2] = (_Float16)lo[2]; Bf[3] = (_Float16)lo[3];
        Bf[4] = (_Float16)hi[0]; Bf[5] = (_Float16)hi[1];
        Bf[6] = (_Float16)hi[2]; Bf[7] = (_Float16)hi[3];
        const _Float16* wp = Wh + ((s * 4 + g) << 10) + (c << 3);
#pragma unroll
        for (int mt = 0; mt < 8; ++mt) {
            f16x8 Af = *(const f16x8*)&wp[mt << 7];
            Cf[mt] = __builtin_amdgcn_mfma_f32_16x16x32_f16(Af, Bf, Cf[mt], 0, 0, 0);
        }
    }
    // lane holds mx[mt*16 + g*4 + r][node0 + w*16 + c] in Cf[mt][r]

    // ---- per-node epilogue (node = bnode; 4 lanes per node via quads)
    float pm = 0.f, pd = 0.f;
    const float4* ps4 = (const float4*)ps;
#pragma unroll
    for (int mt = 0; mt < 8; ++mt) {
        float4 pv = ps4[mt * 4 + g];
        pm = fmaf(Cf[mt][0], Cf[mt][0], pm);
        pm = fmaf(Cf[mt][1], Cf[mt][1], pm);
        pm = fmaf(Cf[mt][2], Cf[mt][2], pm);
        pm = fmaf(Cf[mt][3], Cf[mt][3], pm);
        pd = fmaf(Cf[mt][0], pv.x, pd);
        pd = fmaf(Cf[mt][1], pv.y, pd);
        pd = fmaf(Cf[mt][2], pv.z, pd);
        pd = fmaf(Cf[mt][3], pv.w, pd);
    }
    float xn2 = px;
    xn2 += __shfl_xor(xn2, 16); xn2 += __shfl_xor(xn2, 32);   // ||x||^2 (exact fp32)
    pm  += __shfl_xor(pm, 16);  pm  += __shfl_xor(pm, 32);    // ||mx||^2
    pd  += __shfl_xor(pd, 16);  pd  += __shfl_xor(pd, 32);    // <mx, p>

    float xn      = fmaxf(sqrtf(xn2), MINN);
    float mxn_raw = sqrtf(pm);
    float mxn     = fmaxf(mxn_raw, MINN);
    float alpha   = __fdividef(tanh_fast(__fdividef(mxn, xn) * artanh_fast(xn)), mxn);
    if (mxn_raw <= 1e-10f) alpha = 0.f;     // zero-row guard

    float x2  = alpha * alpha * pm;
    float xy  = alpha * pd;
    float den = fmaxf(fmaf(x2, y2, 1.f + 2.f * xy), MINN);
    float ca  = __fdividef((1.f + 2.f * xy + y2) * alpha, den);
    float cb  = __fdividef(1.f - x2, den);

    // ||h||^2 analytically: h = ca*mx + cb*p
    float hn2 = ca * ca * pm + 2.f * ca * cb * pd + cb * cb * y2;
    float hn  = fmaxf(sqrtf(hn2), MINN);
    float lsc = __fdividef(artanh_fast(hn), hn);
    float s1  = lsc * ca, s2 = lsc * cb;

    // ---- pack to fp16 via LDS transpose (overlay own wave's dead x slice;
    // wave-private region, LDS ops in-order within a wave -> no barrier needed)
    uint2* lout = (uint2*)((char*)xs + (size_t)w * 8192);
#pragma unroll
    for (int mt = 0; mt < 8; ++mt) {
        float4 pv = ps4[mt * 4 + g];
        H4 u;
        u.h[0] = (_Float16)fmaf(s1, Cf[mt][0], s2 * pv.x);
        u.h[1] = (_Float16)fmaf(s1, Cf[mt][1], s2 * pv.y);
        u.h[2] = (_Float16)fmaf(s1, Cf[mt][2], s2 * pv.z);
        u.h[3] = (_Float16)fmaf(s1, Cf[mt][3], s2 * pv.w);
        lout[c * 33 + mt * 4 + g] = u.u2;   // col = mt*4+g holds dims 4col..4col+3
    }
    __syncthreads();

    // ---- coalesced copy-out
    for (int it = 0; it < 8; ++it) {
        int lin  = it * BLK + t;        // 2048 uint2
        int node = lin >> 5;
        int col  = lin & 31;
        int gn   = node0 + node;
        if (gn < N) {
            const uint2* lsrc = (const uint2*)((const char*)xs + (size_t)(node >> 4) * 8192);
            ht[(size_t)gn * 32 + col] = lsrc[(node & 15) * 33 + col];
        }
    }
}

// ---------------------------------------------------------------------------
// CSR build: memset -> (hist fused in k_node) -> scan1 -> scan2 -> scatter
// ---------------------------------------------------------------------------
__global__ __launch_bounds__(256) void k_scan1(
    const int* __restrict__ cnt, int* __restrict__ ptr,
    int* __restrict__ part, int N)
{
    __shared__ int s[256];
    int t = threadIdx.x;
    int base = blockIdx.x * 1024 + t * 4;
    int v0 = 0, v1 = 0, v2 = 0, v3 = 0;
    if (base + 3 < N) {
        int4 q = *(const int4*)&cnt[base];
        v0 = q.x; v1 = q.y; v2 = q.z; v3 = q.w;
    } else {
        if (base + 0 < N) v0 = cnt[base + 0];
        if (base + 1 < N) v1 = cnt[base + 1];
        if (base + 2 < N) v2 = cnt[base + 2];
        if (base + 3 < N) v3 = cnt[base + 3];
    }
    int sum = v0 + v1 + v2 + v3;
    s[t] = sum;
    __syncthreads();
    for (int off = 1; off < 256; off <<= 1) {
        int xv = (t >= off) ? s[t - off] : 0;
        __syncthreads();
        s[t] += xv;
        __syncthreads();
    }
    int excl = s[t] - sum;
    if (t == 255) part[blockIdx.x] = s[255];
    int r = excl;
    if (base + 0 < N) ptr[base + 0] = r; r += v0;
    if (base + 1 < N) ptr[base + 1] = r; r += v1;
    if (base + 2 < N) ptr[base + 2] = r; r += v2;
    if (base + 3 < N) ptr[base + 3] = r;
}

__global__ __launch_bounds__(256) void k_scan2(int* __restrict__ part, int nc) {
    __shared__ int s[256];
    int t = threadIdx.x;
    int v = (t < nc) ? part[t] : 0;
    s[t] = v;
    __syncthreads();
    for (int off = 1; off < 256; off <<= 1) {
        int xv = (t >= off) ? s[t - off] : 0;
        __syncthreads();
        s[t] += xv;
        __syncthreads();
    }
    if (t < nc) part[t] = s[t] - v;   // exclusive
}

// scatter with chunk-offset add folded in.
// sorted[pos] = (src byte-offset into ht, weight bits)
__global__ void k_scatter(const int* __restrict__ ei, const float* __restrict__ ew,
                          int* __restrict__ ptr, const int* __restrict__ part,
                          int2* __restrict__ sorted, int E)
{
    int e = blockIdx.x * 256 + threadIdx.x;
    if (e >= E) return;
    int src = ei[e];
    int dst = ei[E + e];
    float w = ew[e];
    int pos = atomicAdd(&ptr[dst], 1) + part[dst >> 10];
    sorted[pos] = make_int2(src << 8, __float_as_int(w));
}

// ---------------------------------------------------------------------------
// Fused aggregation + epilogue: 16 lanes per node (4 nodes per wave64).
// Lane owns dims 8*li .. 8*li+7 (uint4 = 16 B per gathered row).
// h2_t = logmap0(expmap0(agg)) == agg (identity within fp32 tolerance).
// ---------------------------------------------------------------------------
__global__ __launch_bounds__(256) void k_agg_final(
    const char* __restrict__ htb, const int* __restrict__ ptr,
    const int* __restrict__ part, const int2* __restrict__ sorted,
    const float* __restrict__ a_in, float* __restrict__ out, int N)
{
    const int t   = threadIdx.x;
    const int li  = t & 15;          // lane within 16-lane group
    const int grp = t >> 4;          // group within block (0..15)
    const int n   = blockIdx.x * 16 + grp;
    if (n >= N) return;
    const float a = a_in[0];

    // own row (agg starts at h_t[n])
    H8 own; own.u4 = *(const uint4*)(htb + (size_t)n * 256 + li * 16);
    float acc[8];
#pragma unroll
    for (int k = 0; k < 8; ++k) acc[k] = (float)own.h[k];

    int s0 = (n > 0) ? (ptr[n - 1] + part[(n - 1) >> 10]) : 0;
    int e0 = ptr[n] + part[n >> 10];

    const int lioff = li * 16;
    int j = s0;
    for (; j + 2 <= e0; j += 2) {
        int2 d0 = sorted[j];
        int2 d1 = sorted[j + 1];
        H8 g0, g1;
        g0.u4 = *(const uint4*)(htb + (unsigned)d0.x + lioff);
        g1.u4 = *(const uint4*)(htb + (unsigned)d1.x + lioff);
        float w0 = __int_as_float(d0.y);
        float w1 = __int_as_float(d1.y);
#pragma unroll
        for (int k = 0; k < 8; ++k) acc[k] = fmaf((float)g0.h[k], w0, acc[k]);
#pragma unroll
        for (int k = 0; k < 8; ++k) acc[k] = fmaf((float)g1.h[k], w1, acc[k]);
    }
    if (j < e0) {
        int2 d = sorted[j];
        H8 g; g.u4 = *(const uint4*)(htb + (unsigned)d.x + lioff);
        float w = __int_as_float(d.y);
#pragma unroll
        for (int k = 0; k < 8; ++k) acc[k] = fmaf((float)g.h[k], w, acc[k]);
    }

    // h2_t = acc; PReLU
    float pv = 0.f;
#pragma unroll
    for (int k = 0; k < 8; ++k) {
        float v = acc[k];
        v = (v >= 0.f) ? v : a * v;
        acc[k] = v;
        pv = fmaf(v, v, pv);
    }
    float m2 = red16(pv);
    float rc = fmaxf(sqrtf(m2), MINN);
    float te = tanh_fast(rc);
    // project(expmap0): scale = min(tanh(rc), maxnorm) / rc
    const float maxn = 1.0f - BALLEPS;
    float fsc = __fdividef(fminf(fmaxf(te, MINN), maxn), rc);

    float4 o0 = make_float4(fsc * acc[0], fsc * acc[1], fsc * acc[2], fsc * acc[3]);
    float4 o1 = make_float4(fsc * acc[4], fsc * acc[5], fsc * acc[6], fsc * acc[7]);
    float4* orow = (float4*)(out + (size_t)n * D);
    orow[li * 2 + 0] = o0;
    orow[li * 2 + 1] = o1;
}

// ---------------------------------------------------------------------------
extern "C" void kernel_launch(void* const* d_in, const int* in_sizes, int n_in,
                              void* d_out, int out_size, void* d_ws, size_t ws_size,
                              hipStream_t stream)
{
    const float* x  = (const float*)d_in[0];
    const int*   ei = (const int*)  d_in[1];
    const float* ew = (const float*)d_in[2];
    const float* W  = (const float*)d_in[3];
    const float* b  = (const float*)d_in[4];
    const float* a  = (const float*)d_in[5];
    float* out = (float*)d_out;

    const int N = in_sizes[0] / D;
    const int E = in_sizes[1] / 2;

    // workspace carve-up (~31.25 MB)
    char* ws = (char*)d_ws;
    size_t HT_B    = (size_t)N * D * 2;          // fp16 h_t
    uint2*     ht     = (uint2*)ws;
    int*       cnt    = (int*)(ws + HT_B);
    int*       ptr    = (int*)(ws + HT_B + (size_t)N * 4);
    int*       part   = (int*)(ws + HT_B + (size_t)N * 8);
    int2*      sorted = (int2*)(ws + HT_B + (size_t)N * 8 + 1024);
    _Float16*  Wh     = (_Float16*)(ws + HT_B + (size_t)N * 8 + 1024 + (size_t)E * 8);

    int nc  = (N + 1023) / 1024;    // scan chunks
    int nb1 = (N + 63) / 64;        // k_node blocks
    int eslice = (E + nb1 - 1) / nb1;

    hipMemsetAsync(cnt, 0, (size_t)N * 4, stream);
    k_wcvt<<<8, 256, 0, stream>>>(W, Wh);
    k_node_mfma<<<nb1, BLK, 0, stream>>>(x, Wh, b, ht, N, ei, cnt, E, eslice);
    k_scan1<<<nc, 256, 0, stream>>>(cnt, ptr, part, N);
    k_scan2<<<1, 256, 0, stream>>>(part, nc);
    k_scatter<<<(E + 255) / 256, 256, 0, stream>>>(ei, ew, ptr, part, sorted, E);
    k_agg_final<<<(N + 15) / 16, 256, 0, stream>>>((const char*)ht, ptr, part, sorted, a, out, N);
}